// Round 1
// baseline (531.424 us; speedup 1.0000x reference)
//
#include <hip/hip_runtime.h>
#include <math.h>

#pragma clang fp contract(off)

#define BB   8
#define NGT  60
#define LL   21504
#define CC   15
#define KTOP 13
#define BGI  15
#define EPSF 1e-9f

// AABB of rotated box, replicating reference _box_min_max op order.
// returns (mnx, mxx, mny, mxy)
__device__ __forceinline__ float4 rbox_aabb(float cx, float cy, float w, float h, float r) {
    float cr = (float)cos((double)r);
    float sr = (float)sin((double)r);
    float dx = (w * 0.5f) * cr;
    float dy = (h * 0.5f) * sr;
    float xs[4] = {cx - dx, cx + dx, cx + dx, cx - dx};
    float ys[4] = {cy - dy, cy - dy, cy + dy, cy + dy};
    float mnx = 1e30f, mxx = -1e30f, mny = 1e30f, mxy = -1e30f;
#pragma unroll
    for (int k = 0; k < 4; ++k) {
        float tx = xs[k] - cx, ty = ys[k] - cy;
        float xr = (cx + tx * cr) - ty * sr;
        float yr = (cy + tx * sr) + ty * cr;
        mnx = fminf(mnx, xr); mxx = fmaxf(mxx, xr);
        mny = fminf(mny, yr); mxy = fmaxf(mxy, yr);
    }
    return make_float4(mnx, mxx, mny, mxy);
}

// g = gt AABB (box1), p = pred AABB (box2); a1,a2 = w*h areas
__device__ __forceinline__ float iou_pair(float4 g, float a1, float4 p, float a2) {
    float iw = fmaxf(fminf(g.y, p.y) - fmaxf(g.x, p.x), 0.0f);
    float ih = fmaxf(fminf(g.w, p.w) - fmaxf(g.z, p.z), 0.0f);
    float inter = iw * ih;
    float denom = ((a1 + a2) - inter) + EPSF;
    float q = inter / denom;
    return fminf(fmaxf(q, 0.0f), 1.0f);
}

// ---------- prep kernels ----------
__global__ void prep_gt_kernel(const float* __restrict__ gt,     // (B*NGT,5)
                               const float* __restrict__ pad,    // (B*NGT)
                               float4* __restrict__ gbox,        // AABB
                               float4* __restrict__ gtrig,       // (cos,sin,area,pad)
                               float4* __restrict__ ggeom) {     // (cx,cy,w/2,h/2)
    int i = blockIdx.x * blockDim.x + threadIdx.x;
    if (i >= BB * NGT) return;
    float cx = gt[i * 5 + 0], cy = gt[i * 5 + 1];
    float w  = gt[i * 5 + 2], h  = gt[i * 5 + 3], r = gt[i * 5 + 4];
    gbox[i] = rbox_aabb(cx, cy, w, h, r);
    float cr = (float)cos((double)r);
    float sr = (float)sin((double)r);
    gtrig[i] = make_float4(cr, sr, w * h, pad[i]);
    ggeom[i] = make_float4(cx, cy, w * 0.5f, h * 0.5f);
}

__global__ void prep_pred_kernel(const float* __restrict__ pr,   // (B*LL,5)
                                 float4* __restrict__ pbox,
                                 float* __restrict__ parea) {
    int i = blockIdx.x * blockDim.x + threadIdx.x;
    if (i >= BB * LL) return;
    float cx = pr[i * 5 + 0], cy = pr[i * 5 + 1];
    float w  = pr[i * 5 + 2], h  = pr[i * 5 + 3], r = pr[i * 5 + 4];
    pbox[i] = rbox_aabb(cx, cy, w, h, r);
    parea[i] = w * h;
}

// ---------- metric: m[b,i,j] = score(b,j,label_i) * iou^6 * in_gts ----------
__global__ void metric_kernel(const float* __restrict__ ps,      // (B,L,C)
                              const int* __restrict__ labels,    // (B*NGT)
                              const float* __restrict__ anch,    // (L,2)
                              const float4* __restrict__ pbox,
                              const float* __restrict__ parea,
                              const float4* __restrict__ gbox,
                              const float4* __restrict__ gtrig,
                              const float4* __restrict__ ggeom,
                              float* __restrict__ metric) {      // (B,NGT,L)
    __shared__ float4 sB[NGT], sT[NGT], sG[NGT];
    __shared__ int sL[NGT];
    int b = blockIdx.y;
    int t = threadIdx.x;
    if (t < NGT) {
        sB[t] = gbox[b * NGT + t];
        sT[t] = gtrig[b * NGT + t];
        sG[t] = ggeom[b * NGT + t];
        sL[t] = labels[b * NGT + t];
    }
    __syncthreads();
    int j = blockIdx.x * blockDim.x + t;
    if (j >= LL) return;
    float4 pb = pbox[b * LL + j];
    float a2  = parea[b * LL + j];
    float px  = anch[2 * j], py = anch[2 * j + 1];
    float row[CC];
#pragma unroll
    for (int c = 0; c < CC; ++c) row[c] = ps[(size_t)(b * LL + j) * CC + c];
    for (int i = 0; i < NGT; ++i) {
        float iou = iou_pair(sB[i], sT[i].z, pb, a2);
        float dx = px - sG[i].x, dy = py - sG[i].y;
        float xl = dx * sT[i].x + dy * sT[i].y;
        float yl = dy * sT[i].x - dx * sT[i].y;
        bool ing = (fabsf(xl) <= sG[i].z) && (fabsf(yl) <= sG[i].w);
        float i2 = iou * iou;
        float m = row[sL[i]] * (i2 * i2 * i2);
        metric[(size_t)(b * NGT + i) * LL + j] = ing ? m : 0.0f;
    }
}

// ---------- topk: one block per (b,i) row; 13 rounds of bounded argmax ----------
__global__ void topk_kernel(const float* __restrict__ metric,
                            const float4* __restrict__ gtrig,
                            const float4* __restrict__ ggeom,
                            const float* __restrict__ anch,
                            int* __restrict__ cnt,
                            int* __restrict__ claim) {
    int bi = blockIdx.x;            // b*NGT + i
    int b = bi / NGT, i = bi % NGT;
    float4 tg = gtrig[bi];
    if (tg.w == 0.0f) return;       // pad_gt_mask == 0, uniform per block
    const float* row = metric + (size_t)bi * LL;
    __shared__ float sv[256];
    __shared__ int   si[256];
    int t = threadIdx.x;
    float pv = __builtin_inff();    // lexicographic bound from previous pick
    int   pi = -1;
    for (int r = 0; r < KTOP; ++r) {
        float bv = -1.0f; int bj = 0x7fffffff;
        for (int j = t; j < LL; j += 256) {
            float v = row[j];
            bool q = (v < pv) || (v == pv && j > pi);
            if (q && (v > bv || (v == bv && j < bj))) { bv = v; bj = j; }
        }
        sv[t] = bv; si[t] = bj;
        __syncthreads();
        for (int s = 128; s > 0; s >>= 1) {
            if (t < s) {
                if (sv[t + s] > sv[t] || (sv[t + s] == sv[t] && si[t + s] < si[t])) {
                    sv[t] = sv[t + s]; si[t] = si[t + s];
                }
            }
            __syncthreads();
        }
        float svv = sv[0]; int sj = si[0];
        __syncthreads();
        pv = svv; pi = sj;
        if (t == 0) {
            bool in = (svv > 0.0f);  // positive metric implies in_gts
            if (!in) {               // zero-metric pick: explicit in_gts test
                float4 g = ggeom[bi];
                float px = anch[2 * sj], py = anch[2 * sj + 1];
                float dx = px - g.x, dy = py - g.y;
                float xl = dx * tg.x + dy * tg.y;
                float yl = dy * tg.x - dx * tg.y;
                in = (fabsf(xl) <= g.z) && (fabsf(yl) <= g.w);
            }
            if (in) {
                atomicAdd(&cnt[b * LL + sj], 1);
                atomicMax(&claim[b * LL + sj], i);
            }
        }
    }
}

// ---------- resolve: assign one gt (or none) per anchor; per-gt maxes ----------
__global__ void resolve_kernel(const float* __restrict__ ps,
                               const int* __restrict__ labels,
                               const float4* __restrict__ pbox,
                               const float* __restrict__ parea,
                               const float4* __restrict__ gbox,
                               const float4* __restrict__ gtrig,
                               const float* __restrict__ metric,
                               const int* __restrict__ cnt,
                               const int* __restrict__ claim,
                               int* __restrict__ assigned,
                               float* __restrict__ aMetric,
                               unsigned* __restrict__ maxM,
                               unsigned* __restrict__ maxI) {
    __shared__ float4 sB[NGT];
    __shared__ float  sA[NGT];
    int b = blockIdx.y, t = threadIdx.x;
    if (t < NGT) { sB[t] = gbox[b * NGT + t]; sA[t] = gtrig[b * NGT + t].z; }
    __syncthreads();
    int j = blockIdx.x * blockDim.x + t;
    if (j >= LL) return;
    int p = b * LL + j;
    int c = cnt[p];
    if (c == 0) { assigned[p] = -1; aMetric[p] = 0.0f; return; }
    float4 pb = pbox[p];
    float a2 = parea[p];
    int a; float m, iouv;
    if (c == 1) {
        a = claim[p];
        iouv = iou_pair(sB[a], sA[a], pb, a2);
        m = metric[(size_t)(b * NGT + a) * LL + j];   // in_gts==1 for claims
    } else {
        float best = -1.0f; int bi = 0;
        for (int i = 0; i < NGT; ++i) {
            float v = iou_pair(sB[i], sA[i], pb, a2);
            if (v > best) { best = v; bi = i; }       // ties -> lowest index
        }
        a = bi; iouv = best;
        float sc = ps[(size_t)p * CC + labels[b * NGT + a]];
        float i2 = iouv * iouv;
        m = sc * (i2 * i2 * i2);                      // no in_gts factor here
    }
    assigned[p] = a;
    aMetric[p] = m;
    atomicMax(&maxM[b * NGT + a], __float_as_uint(m));
    atomicMax(&maxI[b * NGT + a], __float_as_uint(iouv));
}

// ---------- finalize: write all 5 outputs (float32, concatenated) ----------
__global__ void finalize_kernel(const float* __restrict__ gt,     // (B*NGT,5)
                                const int* __restrict__ labels,
                                const int* __restrict__ crowd,
                                const int* __restrict__ assigned,
                                const float* __restrict__ aMetric,
                                const unsigned* __restrict__ maxM,
                                const unsigned* __restrict__ maxI,
                                float* __restrict__ out) {
    int b = blockIdx.y;
    int j = blockIdx.x * blockDim.x + threadIdx.x;
    if (j >= LL) return;
    int p = b * LL + j;
    int a = assigned[p];
    bool pos = (a >= 0);
    int idx = pos ? a : 0;
    int lab = labels[b * NGT + idx];
    int cw  = crowd[b * NGT + idx];
    const size_t O0 = 0;
    const size_t O1 = (size_t)BB * LL;
    const size_t O2 = O1 + (size_t)BB * LL * 5;
    const size_t O3 = O2 + (size_t)BB * LL * CC;
    const size_t O4 = O3 + (size_t)BB * LL;
    out[O0 + p] = pos ? (float)lab : (float)BGI;
    const float* gb = gt + (size_t)(b * NGT + idx) * 5;
#pragma unroll
    for (int k = 0; k < 5; ++k) out[O1 + (size_t)p * 5 + k] = gb[k];
    float per = 0.0f;
    if (pos) {
        float mm = __uint_as_float(maxM[b * NGT + a]);
        float mi = __uint_as_float(maxI[b * NGT + a]);
        per = aMetric[p] / (mm + EPSF) * mi;
    }
#pragma unroll
    for (int c = 0; c < CC; ++c) {
        float s = (pos && cw == 0 && c == lab) ? per : 0.0f;
        out[O2 + (size_t)p * CC + c] = s;
    }
    out[O3 + p] = (float)idx;
    out[O4 + p] = (float)cw;
}

extern "C" void kernel_launch(void* const* d_in, const int* in_sizes, int n_in,
                              void* d_out, int out_size, void* d_ws, size_t ws_size,
                              hipStream_t stream) {
    const float* pred_scores = (const float*)d_in[0];
    const float* pred_rboxes = (const float*)d_in[1];
    const float* anchor_pts  = (const float*)d_in[2];
    const int*   gt_labels   = (const int*)d_in[3];
    const float* gt_bboxes   = (const float*)d_in[4];
    // d_in[5] = gt_poses (unused)
    const int*   gt_crowd    = (const int*)d_in[6];
    const float* pad_gt      = (const float*)d_in[7];
    float* out = (float*)d_out;

    char* ws = (char*)d_ws;
    size_t off = 0;
    auto alloc = [&](size_t bytes) {
        void* pp = ws + off;
        off += (bytes + 255) & ~(size_t)255;
        return pp;
    };
    float*  metric = (float*)alloc((size_t)BB * NGT * LL * 4);
    float4* pbox   = (float4*)alloc((size_t)BB * LL * 16);
    float*  parea  = (float*)alloc((size_t)BB * LL * 4);
    float4* gbox   = (float4*)alloc((size_t)BB * NGT * 16);
    float4* gtrig  = (float4*)alloc((size_t)BB * NGT * 16);
    float4* ggeom  = (float4*)alloc((size_t)BB * NGT * 16);
    // zero block: cnt | claim | maxM | maxI (contiguous)
    size_t zbytes = ((size_t)2 * BB * LL + 2 * BB * NGT) * 4;
    char* zbase = (char*)alloc(zbytes);
    int* cnt        = (int*)zbase;
    int* claim      = cnt + (size_t)BB * LL;
    unsigned* maxM  = (unsigned*)(claim + (size_t)BB * LL);
    unsigned* maxI  = maxM + (size_t)BB * NGT;
    int*   assigned = (int*)alloc((size_t)BB * LL * 4);
    float* aMetric  = (float*)alloc((size_t)BB * LL * 4);

    hipMemsetAsync(zbase, 0, zbytes, stream);

    prep_gt_kernel<<<dim3((BB * NGT + 255) / 256), dim3(256), 0, stream>>>(
        gt_bboxes, pad_gt, gbox, gtrig, ggeom);
    prep_pred_kernel<<<dim3((BB * LL + 255) / 256), dim3(256), 0, stream>>>(
        pred_rboxes, pbox, parea);
    metric_kernel<<<dim3(LL / 256, BB), dim3(256), 0, stream>>>(
        pred_scores, gt_labels, anchor_pts, pbox, parea, gbox, gtrig, ggeom, metric);
    topk_kernel<<<dim3(BB * NGT), dim3(256), 0, stream>>>(
        metric, gtrig, ggeom, anchor_pts, cnt, claim);
    resolve_kernel<<<dim3(LL / 256, BB), dim3(256), 0, stream>>>(
        pred_scores, gt_labels, pbox, parea, gbox, gtrig, metric, cnt, claim,
        assigned, aMetric, maxM, maxI);
    finalize_kernel<<<dim3(LL / 256, BB), dim3(256), 0, stream>>>(
        gt_bboxes, gt_labels, gt_crowd, assigned, aMetric, maxM, maxI, out);
}

// Round 2
// 219.486 us; speedup vs baseline: 2.4212x; 2.4212x over previous
//
#include <hip/hip_runtime.h>
#include <math.h>

#pragma clang fp contract(off)

#define BB   8
#define NGT  60
#define LL   21504
#define CC   15
#define KTOP 13
#define BGI  15
#define EPSF 1e-9f

// AABB of rotated box, replicating reference _box_min_max op order.
__device__ __forceinline__ float4 rbox_aabb(float cx, float cy, float w, float h, float r) {
    float cr = (float)cos((double)r);
    float sr = (float)sin((double)r);
    float dx = (w * 0.5f) * cr;
    float dy = (h * 0.5f) * sr;
    float xs[4] = {cx - dx, cx + dx, cx + dx, cx - dx};
    float ys[4] = {cy - dy, cy - dy, cy + dy, cy + dy};
    float mnx = 1e30f, mxx = -1e30f, mny = 1e30f, mxy = -1e30f;
#pragma unroll
    for (int k = 0; k < 4; ++k) {
        float tx = xs[k] - cx, ty = ys[k] - cy;
        float xr = (cx + tx * cr) - ty * sr;
        float yr = (cy + tx * sr) + ty * cr;
        mnx = fminf(mnx, xr); mxx = fmaxf(mxx, xr);
        mny = fminf(mny, yr); mxy = fmaxf(mxy, yr);
    }
    return make_float4(mnx, mxx, mny, mxy);
}

__device__ __forceinline__ float iou_pair(float4 g, float a1, float4 p, float a2) {
    float iw = fmaxf(fminf(g.y, p.y) - fmaxf(g.x, p.x), 0.0f);
    float ih = fmaxf(fminf(g.w, p.w) - fmaxf(g.z, p.z), 0.0f);
    float inter = iw * ih;
    float denom = ((a1 + a2) - inter) + EPSF;
    float q = inter / denom;
    return fminf(fmaxf(q, 0.0f), 1.0f);
}

// ---------- prep: gt boxes ----------
__global__ void prep_gt_kernel(const float* __restrict__ gt,
                               const float* __restrict__ pad,
                               float4* __restrict__ gbox,     // AABB
                               float4* __restrict__ gtrig,    // (cos,sin,area,pad)
                               float4* __restrict__ ggeom) {  // (cx,cy,w/2,h/2)
    int i = blockIdx.x * blockDim.x + threadIdx.x;
    if (i >= BB * NGT) return;
    float cx = gt[i * 5 + 0], cy = gt[i * 5 + 1];
    float w  = gt[i * 5 + 2], h  = gt[i * 5 + 3], r = gt[i * 5 + 4];
    gbox[i] = rbox_aabb(cx, cy, w, h, r);
    float cr = (float)cos((double)r);
    float sr = (float)sin((double)r);
    gtrig[i] = make_float4(cr, sr, w * h, pad[i]);
    ggeom[i] = make_float4(cx, cy, w * 0.5f, h * 0.5f);
}

// ---------- prep: pred boxes + score transpose (B,L,C)->(B,C,L) ----------
__global__ void prep_pred_kernel(const float* __restrict__ pr,
                                 const float* __restrict__ ps,
                                 float4* __restrict__ pbox,
                                 float* __restrict__ parea,
                                 float* __restrict__ psT) {
    int i = blockIdx.x * blockDim.x + threadIdx.x;  // b*LL + j
    if (i >= BB * LL) return;
    float cx = pr[i * 5 + 0], cy = pr[i * 5 + 1];
    float w  = pr[i * 5 + 2], h  = pr[i * 5 + 3], r = pr[i * 5 + 4];
    pbox[i] = rbox_aabb(cx, cy, w, h, r);
    parea[i] = w * h;
    int b = i / LL, j = i % LL;
#pragma unroll
    for (int c = 0; c < CC; ++c)
        psT[((size_t)b * CC + c) * LL + j] = ps[(size_t)i * CC + c];  // coalesced write
}

// ---------- fused metric + single-pass top-13 ----------
// One block per (b,i) GT row. Each thread keeps a sorted local top-13
// (value desc, index asc) of its 84 strided elements, then a 13-round
// head merge selects the global top-13 with top_k-stable tie-breaking.
__global__ __launch_bounds__(256) void topk_kernel(
        const float* __restrict__ psT,
        const int* __restrict__ labels,
        const float* __restrict__ anch,
        const float4* __restrict__ pbox,
        const float* __restrict__ parea,
        const float4* __restrict__ gbox,
        const float4* __restrict__ gtrig,
        const float4* __restrict__ ggeom,
        int* __restrict__ cnt,
        int* __restrict__ claim) {
    int bi = blockIdx.x;            // b*NGT + i
    int b = bi / NGT, i = bi % NGT;
    float4 tg = gtrig[bi];
    if (tg.w == 0.0f) return;       // pad_gt_mask == 0 (uniform per block)
    float4 g  = gbox[bi];
    float4 gg = ggeom[bi];
    float  a1 = tg.z;
    int   lab = labels[bi];
    const float*  srow = psT + ((size_t)b * CC + lab) * LL;
    const float4* pb   = pbox + (size_t)b * LL;
    const float*  pa   = parea + (size_t)b * LL;
    const float2* an2  = (const float2*)anch;
    int t = threadIdx.x;

    float lv[KTOP]; int li[KTOP];
#pragma unroll
    for (int k = 0; k < KTOP; ++k) { lv[k] = -1.0f; li[k] = 0x7fffffff; }

    // single pass: indices ascend per thread, so strictly-greater insertion
    // preserves (value desc, index asc) order exactly like jax.lax.top_k
    for (int j = t; j < LL; j += 256) {
        float4 p = pb[j];
        float a2 = pa[j];
        float iou = iou_pair(g, a1, p, a2);
        float2 ap = an2[j];
        float dx = ap.x - gg.x, dy = ap.y - gg.y;
        float xl = dx * tg.x + dy * tg.y;
        float yl = dy * tg.x - dx * tg.y;
        bool ing = (fabsf(xl) <= gg.z) && (fabsf(yl) <= gg.w);
        float i2 = iou * iou;
        float v = ing ? (srow[j] * (i2 * i2 * i2)) : 0.0f;
        if (v > lv[KTOP - 1]) {
            lv[KTOP - 1] = v; li[KTOP - 1] = j;
#pragma unroll
            for (int k = KTOP - 1; k > 0; --k) {
                bool sw = lv[k] > lv[k - 1];
                float tv = sw ? lv[k - 1] : lv[k];
                int   ti = sw ? li[k - 1] : li[k];
                lv[k - 1] = sw ? lv[k] : lv[k - 1];
                li[k - 1] = sw ? li[k] : li[k - 1];
                lv[k] = tv; li[k] = ti;
            }
        }
    }

    // 13-round merge over the 256 sorted list heads
    __shared__ float wv[4]; __shared__ int wi[4];
    __shared__ int bpj_s;
    for (int r = 0; r < KTOP; ++r) {
        float ov = lv[0]; int oj = li[0];
#pragma unroll
        for (int off = 32; off > 0; off >>= 1) {
            float v2 = __shfl_xor(ov, off, 64);
            int   j2 = __shfl_xor(oj, off, 64);
            if (v2 > ov || (v2 == ov && j2 < oj)) { ov = v2; oj = j2; }
        }
        if ((t & 63) == 0) { wv[t >> 6] = ov; wi[t >> 6] = oj; }
        __syncthreads();
        if (t == 0) {
            float bv = wv[0]; int bj = wi[0];
#pragma unroll
            for (int k = 1; k < 4; ++k)
                if (wv[k] > bv || (wv[k] == bv && wi[k] < bj)) { bv = wv[k]; bj = wi[k]; }
            bpj_s = bj;
            bool in = (bv > 0.0f);   // positive metric implies in_gts
            if (!in) {               // zero-metric pick: explicit in_gts test
                float2 ap = ((const float2*)anch)[bj];
                float dx = ap.x - gg.x, dy = ap.y - gg.y;
                float xl = dx * tg.x + dy * tg.y;
                float yl = dy * tg.x - dx * tg.y;
                in = (fabsf(xl) <= gg.z) && (fabsf(yl) <= gg.w);
            }
            if (in) {
                atomicAdd(&cnt[b * LL + bj], 1);
                atomicMax(&claim[b * LL + bj], i);
            }
        }
        __syncthreads();
        if (li[0] == bpj_s) {        // unique j -> exactly one thread pops
#pragma unroll
            for (int k = 0; k < KTOP - 1; ++k) { lv[k] = lv[k + 1]; li[k] = li[k + 1]; }
            lv[KTOP - 1] = -1.0f; li[KTOP - 1] = 0x7fffffff;
        }
    }
}

// ---------- resolve: assign one gt (or none) per anchor; per-gt maxes ----------
__global__ void resolve_kernel(const float* __restrict__ psT,
                               const int* __restrict__ labels,
                               const float4* __restrict__ pbox,
                               const float* __restrict__ parea,
                               const float4* __restrict__ gbox,
                               const float4* __restrict__ gtrig,
                               const int* __restrict__ cnt,
                               const int* __restrict__ claim,
                               int* __restrict__ assigned,
                               float* __restrict__ aMetric,
                               unsigned* __restrict__ maxM,
                               unsigned* __restrict__ maxI) {
    __shared__ float4 sB[NGT];
    __shared__ float  sA[NGT];
    int b = blockIdx.y, t = threadIdx.x;
    if (t < NGT) { sB[t] = gbox[b * NGT + t]; sA[t] = gtrig[b * NGT + t].z; }
    __syncthreads();
    int j = blockIdx.x * blockDim.x + t;
    if (j >= LL) return;
    int p = b * LL + j;
    int c = cnt[p];
    if (c == 0) { assigned[p] = -1; aMetric[p] = 0.0f; return; }
    float4 pb = pbox[p];
    float a2 = parea[p];
    int a; float iouv;
    if (c == 1) {
        a = claim[p];
        iouv = iou_pair(sB[a], sA[a], pb, a2);
    } else {
        float best = -1.0f; int bi = 0;
        for (int i = 0; i < NGT; ++i) {
            float v = iou_pair(sB[i], sA[i], pb, a2);
            if (v > best) { best = v; bi = i; }       // ties -> lowest index
        }
        a = bi; iouv = best;
    }
    // recompute metric bit-identically to topk's value (same op order)
    float sc = psT[((size_t)b * CC + labels[b * NGT + a]) * LL + j];
    float i2 = iouv * iouv;
    float m = sc * (i2 * i2 * i2);
    assigned[p] = a;
    aMetric[p] = m;
    atomicMax(&maxM[b * NGT + a], __float_as_uint(m));
    atomicMax(&maxI[b * NGT + a], __float_as_uint(iouv));
}

// ---------- finalize: write all 5 outputs (float32, concatenated) ----------
__global__ void finalize_kernel(const float* __restrict__ gt,
                                const int* __restrict__ labels,
                                const int* __restrict__ crowd,
                                const int* __restrict__ assigned,
                                const float* __restrict__ aMetric,
                                const unsigned* __restrict__ maxM,
                                const unsigned* __restrict__ maxI,
                                float* __restrict__ out) {
    int b = blockIdx.y;
    int j = blockIdx.x * blockDim.x + threadIdx.x;
    if (j >= LL) return;
    int p = b * LL + j;
    int a = assigned[p];
    bool pos = (a >= 0);
    int idx = pos ? a : 0;
    int lab = labels[b * NGT + idx];
    int cw  = crowd[b * NGT + idx];
    const size_t O0 = 0;
    const size_t O1 = (size_t)BB * LL;
    const size_t O2 = O1 + (size_t)BB * LL * 5;
    const size_t O3 = O2 + (size_t)BB * LL * CC;
    const size_t O4 = O3 + (size_t)BB * LL;
    out[O0 + p] = pos ? (float)lab : (float)BGI;
    const float* gb = gt + (size_t)(b * NGT + idx) * 5;
#pragma unroll
    for (int k = 0; k < 5; ++k) out[O1 + (size_t)p * 5 + k] = gb[k];
    float per = 0.0f;
    if (pos) {
        float mm = __uint_as_float(maxM[b * NGT + a]);
        float mi = __uint_as_float(maxI[b * NGT + a]);
        per = aMetric[p] / (mm + EPSF) * mi;
    }
#pragma unroll
    for (int c = 0; c < CC; ++c) {
        float s = (pos && cw == 0 && c == lab) ? per : 0.0f;
        out[O2 + (size_t)p * CC + c] = s;
    }
    out[O3 + p] = (float)idx;
    out[O4 + p] = (float)cw;
}

extern "C" void kernel_launch(void* const* d_in, const int* in_sizes, int n_in,
                              void* d_out, int out_size, void* d_ws, size_t ws_size,
                              hipStream_t stream) {
    const float* pred_scores = (const float*)d_in[0];
    const float* pred_rboxes = (const float*)d_in[1];
    const float* anchor_pts  = (const float*)d_in[2];
    const int*   gt_labels   = (const int*)d_in[3];
    const float* gt_bboxes   = (const float*)d_in[4];
    // d_in[5] = gt_poses (unused)
    const int*   gt_crowd    = (const int*)d_in[6];
    const float* pad_gt      = (const float*)d_in[7];
    float* out = (float*)d_out;

    char* ws = (char*)d_ws;
    size_t off = 0;
    auto alloc = [&](size_t bytes) {
        void* pp = ws + off;
        off += (bytes + 255) & ~(size_t)255;
        return pp;
    };
    float*  psT   = (float*)alloc((size_t)BB * CC * LL * 4);
    float4* pbox  = (float4*)alloc((size_t)BB * LL * 16);
    float*  parea = (float*)alloc((size_t)BB * LL * 4);
    float4* gbox  = (float4*)alloc((size_t)BB * NGT * 16);
    float4* gtrig = (float4*)alloc((size_t)BB * NGT * 16);
    float4* ggeom = (float4*)alloc((size_t)BB * NGT * 16);
    // zero block: cnt | claim | maxM | maxI (contiguous)
    size_t zbytes = ((size_t)2 * BB * LL + 2 * BB * NGT) * 4;
    char* zbase = (char*)alloc(zbytes);
    int* cnt        = (int*)zbase;
    int* claim      = cnt + (size_t)BB * LL;
    unsigned* maxM  = (unsigned*)(claim + (size_t)BB * LL);
    unsigned* maxI  = maxM + (size_t)BB * NGT;
    int*   assigned = (int*)alloc((size_t)BB * LL * 4);
    float* aMetric  = (float*)alloc((size_t)BB * LL * 4);

    hipMemsetAsync(zbase, 0, zbytes, stream);

    prep_gt_kernel<<<dim3((BB * NGT + 255) / 256), dim3(256), 0, stream>>>(
        gt_bboxes, pad_gt, gbox, gtrig, ggeom);
    prep_pred_kernel<<<dim3((BB * LL + 255) / 256), dim3(256), 0, stream>>>(
        pred_rboxes, pred_scores, pbox, parea, psT);
    topk_kernel<<<dim3(BB * NGT), dim3(256), 0, stream>>>(
        psT, gt_labels, anchor_pts, pbox, parea, gbox, gtrig, ggeom, cnt, claim);
    resolve_kernel<<<dim3(LL / 256, BB), dim3(256), 0, stream>>>(
        psT, gt_labels, pbox, parea, gbox, gtrig, cnt, claim,
        assigned, aMetric, maxM, maxI);
    finalize_kernel<<<dim3(LL / 256, BB), dim3(256), 0, stream>>>(
        gt_bboxes, gt_labels, gt_crowd, assigned, aMetric, maxM, maxI, out);
}